// Round 5
// baseline (1263.222 us; speedup 1.0000x reference)
//
#include <hip/hip_runtime.h>
#include <hip/hip_bf16.h>

#define B_ 8
#define N_ 3136
#define C_ 512
#define NH_ 8
#define HD_ 64
#define FF_ 4096
#define M_ (B_*N_)   // 25088
#define FFCHUNK 12544   // rows per FF chunk (2 chunks)

// ---- workspace layout (byte offsets), total ~219.7 MB ----
#define SZF 51380224LL            // f32 M*512 (also = bf16 64*128*3136)
#define SZH 25690112LL            // bf16 M*512
#define OFF_A    0LL              // f32: kraw (Wkv out), later REUSED as qraw (Wqg out)
#define OFF_KCT  (OFF_A + SZF)    // bf16 kcT[64][128][3136], n-contiguous
#define OFF_XB   (OFF_KCT + SZF)  // bf16 x (alive until Wqg gemm)
#define OFF_VB   (OFF_XB + SZH)   // bf16 v
#define OFF_ATTN (OFF_VB + SZH)   // part[7][64][8192] f32 (14.7MB), later attn bf16
#define OFF_GX2  (OFF_ATTN + SZH) // bf16 g, overwritten in-place by x2
#define OFF_WQGT (OFF_GX2 + SZH)  // bf16 1024x512
#define OFF_WKVT (OFF_WQGT + 1048576LL)
#define OFF_W1T  (OFF_WKVT + 1048576LL)  // bf16 4096x512
#define OFF_W2T  (OFF_W1T + 4194304LL)   // bf16 512x4096
#define OFF_KM   (OFF_W2T + 4194304LL)   // f32 64*128
#define OFF_BMAT (OFF_KM + 32768LL)      // f32 64*8192
#define OFF_Z1   (OFF_BMAT + 2097152LL)  // f32 64*3136
#define OFF_Z2   (OFF_Z1 + 802816LL)
#define OFF_SC   (OFF_Z2 + 802816LL)
#define OFF_PW   (OFF_SC + 2048LL)
#define WS_BYTES (OFF_PW + 2048LL)
// h1b (bf16 12544*4096 = 102,760,448 B) aliases [OFF_A, OFF_XB) exactly (both dead in FF phase).
#define OFF_H1B  0LL

typedef short bfrag __attribute__((ext_vector_type(8)));
typedef float ffrag __attribute__((ext_vector_type(4)));

__device__ __forceinline__ float safe_pow(float x, float p) {
    return x > 0.f ? powf(x, p) : 0.f;
}

__device__ __forceinline__ void gld_lds16(const void* g, void* l) {
    __builtin_amdgcn_global_load_lds(
        (const __attribute__((address_space(1))) unsigned int*)g,
        (__attribute__((address_space(3))) unsigned int*)l, 16, 0, 0);
}

__global__ void zero_kernel(float* __restrict__ p, long long n) {
    long long i = (long long)blockIdx.x*256 + threadIdx.x;
    if (i < n) p[i] = 0.f;
}

__global__ void prep_params(const float* __restrict__ sp, const float* __restrict__ pp,
                            float* __restrict__ sc, float* __restrict__ pw) {
    int c = blockIdx.x * blockDim.x + threadIdx.x;
    if (c < 512) {
        sc[c] = log1pf(expf(sp[c]));
        pw[c] = 1.f + 4.f / (1.f + expf(-pp[c]));
    }
}

__global__ void cvt_bf16_kernel(const float* __restrict__ s, __hip_bfloat16* __restrict__ d,
                                long long n) {
    long long i = ((long long)blockIdx.x*256 + threadIdx.x)*4;
    if (i < n) {
        float4 v = *(const float4*)(s + i);
        union { __hip_bfloat16 h[4]; uint2 u; } t;
        t.h[0] = __float2bfloat16(v.x);
        t.h[1] = __float2bfloat16(v.y);
        t.h[2] = __float2bfloat16(v.z);
        t.h[3] = __float2bfloat16(v.w);
        *(uint2*)(d + i) = t.u;
    }
}

// src R x C fp32 -> dst C x R bf16
__global__ __launch_bounds__(256) void transpose_cvt(const float* __restrict__ s,
        __hip_bfloat16* __restrict__ d, int R, int Cc) {
    __shared__ float t[32][33];
    int c0 = blockIdx.x*32, r0 = blockIdx.y*32;
    int tx = threadIdx.x & 31, ty = threadIdx.x >> 5;
#pragma unroll
    for (int i = 0; i < 32; i += 8)
        t[ty+i][tx] = s[(long long)(r0+ty+i)*Cc + c0+tx];
    __syncthreads();
#pragma unroll
    for (int i = 0; i < 32; i += 8)
        d[(long long)(c0+ty+i)*R + r0+tx] = __float2bfloat16(t[tx][ty+i]);
}

// ---------------- 128x128 bf16 MFMA GEMM ----------------
template<int EPI>
__global__ __launch_bounds__(256) void gemm_mfma(
    const __hip_bfloat16* __restrict__ A, int lda,
    const __hip_bfloat16* __restrict__ Bt, int ldbt,
    int Ktot, int ldo,
    float* __restrict__ o0, __hip_bfloat16* __restrict__ o1,
    const float* __restrict__ p0, const float* __restrict__ p1)
{
    __shared__ __hip_bfloat16 As[128*32];
    __shared__ __hip_bfloat16 Bs[128*32];
    const int tid = threadIdx.x;
    const int lane = tid & 63, w = tid >> 6;
    const int wm = w >> 1, wn = w & 1;
    const int quad = lane >> 4, l16 = lane & 15;
    const int m0 = blockIdx.y * 128, n0 = blockIdx.x * 128;
    const int srow = lane >> 2;          // 0..15
    const int scol = (lane & 3) * 8;     // bf16 elements

    ffrag acc[4][4];
#pragma unroll
    for (int i = 0; i < 4; ++i)
#pragma unroll
        for (int j = 0; j < 4; ++j)
#pragma unroll
            for (int r = 0; r < 4; ++r) acc[i][j][r] = 0.f;

    for (int k0 = 0; k0 < Ktot; k0 += 32) {
        __syncthreads();
#pragma unroll
        for (int t = 0; t < 2; ++t) {
            const __hip_bfloat16* gp = A + (long long)(m0 + t*64 + w*16 + srow)*lda + k0 + scol;
            gld_lds16(gp, As + (t*64 + w*16)*32);
        }
#pragma unroll
        for (int t = 0; t < 2; ++t) {
            const __hip_bfloat16* gp = Bt + (long long)(n0 + t*64 + w*16 + srow)*ldbt + k0 + scol;
            gld_lds16(gp, Bs + (t*64 + w*16)*32);
        }
        __syncthreads();
        bfrag af[4], bf[4];
#pragma unroll
        for (int i = 0; i < 4; ++i)
            af[i] = *(const bfrag*)(As + (wm*64 + i*16 + l16)*32 + quad*8);
#pragma unroll
        for (int j = 0; j < 4; ++j)
            bf[j] = *(const bfrag*)(Bs + (wn*64 + j*16 + l16)*32 + quad*8);
#pragma unroll
        for (int i = 0; i < 4; ++i)
#pragma unroll
            for (int j = 0; j < 4; ++j)
                acc[i][j] = __builtin_amdgcn_mfma_f32_16x16x32_bf16(af[i], bf[j], acc[i][j], 0, 0, 0);
    }

#pragma unroll
    for (int i = 0; i < 4; ++i) {
        int rbase = m0 + wm*64 + i*16 + quad*4;
#pragma unroll
        for (int r = 0; r < 4; ++r) {
            long long grow = rbase + r;
            int nmod = 0;
            if constexpr (EPI == 1) nmod = (int)(grow % N_);
#pragma unroll
            for (int j = 0; j < 4; ++j) {
                int gcol = n0 + wn*64 + j*16 + l16;
                float v = acc[i][j][r];
                if constexpr (EPI == 0) {
                    if (gcol < 512) o0[grow*512 + gcol] = v / p0[gcol];
                    else o1[grow*512 + gcol - 512] = __float2bfloat16(v);
                } else if constexpr (EPI == 1) {
                    if (gcol < 512) o0[grow*512 + gcol] = (v + p1[(long long)nmod*512 + gcol]) / p0[gcol];
                    else o1[grow*512 + gcol - 512] = __float2bfloat16(v);
                } else if constexpr (EPI == 2) {
                    o1[grow*(long long)ldo + gcol] = __float2bfloat16(fmaxf(v + p0[gcol], 0.f));
                } else {
                    o0[grow*512 + gcol] = o0[grow*512 + gcol] + v + p0[gcol];
                }
            }
        }
    }
}

// kcT[zb][d2][n] = safe_pow(+-kraw, p) bf16 (n-contig, MFMA A-layout); km[zb][d2] += sums
__global__ __launch_bounds__(256) void kc_kernel(const float* __restrict__ kraw,
        const float* __restrict__ pw, __hip_bfloat16* __restrict__ kcT,
        float* __restrict__ km)
{
    __shared__ float kt[64][68];   // pad 68: float4-aligned rows, 2-way-free column reads
    int zb = blockIdx.x, nt = blockIdx.y;
    int b = zb >> 3, h = zb & 7;
    int n0 = nt * 64;
    int tid = threadIdx.x;
    {
        int r = tid >> 2, q = (tid & 3) * 16;
        const float* src = kraw + ((long long)(b*N_ + n0 + r))*512 + h*64 + q;
        float4 a0 = *(const float4*)(src);
        float4 a1 = *(const float4*)(src + 4);
        float4 a2 = *(const float4*)(src + 8);
        float4 a3 = *(const float4*)(src + 12);
        *(float4*)&kt[r][q]      = a0;
        *(float4*)&kt[r][q + 4]  = a1;
        *(float4*)&kt[r][q + 8]  = a2;
        *(float4*)&kt[r][q + 12] = a3;
    }
    __syncthreads();
    int d2 = tid >> 1, half = tid & 1;
    int d = d2 & 63;
    bool neg = d2 >= 64;
    float p = pw[h*64 + d];
    float kms = 0.f;
    union { __hip_bfloat16 h8[32]; uint4 u[4]; } buf;
#pragma unroll
    for (int i = 0; i < 32; ++i) {
        float kv = kt[half*32 + i][d];
        float x = neg ? -kv : kv;
        float kc = x > 0.f ? powf(x, p) : 0.f;
        kms += kc;
        buf.h8[i] = __float2bfloat16(kc);
    }
    __hip_bfloat16* dst = kcT + ((long long)zb*128 + d2)*N_ + n0 + half*32;
    *(uint4*)(dst)      = buf.u[0];
    *(uint4*)(dst + 8)  = buf.u[1];
    *(uint4*)(dst + 16) = buf.u[2];
    *(uint4*)(dst + 24) = buf.u[3];
    kms += __shfl_xor(kms, 1);
    if (half == 0) atomicAdd(&km[zb*128 + d2], kms);
}

// part[ks][zb][d2][m] = sum_{n in ks-range} kcT[zb][d2][n] * v[n][m]  via MFMA
// grid (7, 64), 256 thr = 4 waves; wave w owns d2 in [w*32, w*32+32), all m, full k-range 448.
__global__ __launch_bounds__(256) void kvagg_mfma(
    const __hip_bfloat16* __restrict__ kcT,
    const __hip_bfloat16* __restrict__ vb,
    float* __restrict__ part)
{
    __shared__ __hip_bfloat16 vlds[32*66];  // stride 66: conflict-free frag reads
    const int ks = blockIdx.x;     // 0..6
    const int zb = blockIdx.y;     // 0..63
    const int b = zb >> 3, h = zb & 7;
    const int tid = threadIdx.x;
    const int lane = tid & 63, w = tid >> 6;
    const int quad = lane >> 4, l16 = lane & 15;
    const int vrow = tid >> 3, vchunk = tid & 7;

    ffrag acc[2][4];
#pragma unroll
    for (int i = 0; i < 2; ++i)
#pragma unroll
        for (int j = 0; j < 4; ++j)
#pragma unroll
            for (int r = 0; r < 4; ++r) acc[i][j][r] = 0.f;

    const __hip_bfloat16* Abase = kcT + (long long)zb*128*N_;

    for (int s = 0; s < 14; ++s) {
        int klo = ks*448 + s*32;
        uint4 vv = *(const uint4*)(vb + ((long long)(b*N_ + klo + vrow))*512 + h*64 + vchunk*8);
        __syncthreads();
        {
            unsigned* dp = (unsigned*)&vlds[vrow*66 + vchunk*8];
            dp[0] = vv.x; dp[1] = vv.y; dp[2] = vv.z; dp[3] = vv.w;
        }
        __syncthreads();
        bfrag af[2], bf[4];
#pragma unroll
        for (int i = 0; i < 2; ++i)
            af[i] = *(const bfrag*)(Abase + ((long long)(w*32 + i*16 + l16))*N_ + klo + quad*8);
#pragma unroll
        for (int j = 0; j < 4; ++j) {
            bfrag t;
#pragma unroll
            for (int jj = 0; jj < 8; ++jj)
                t[jj] = *(const short*)&vlds[(quad*8 + jj)*66 + j*16 + l16];
            bf[j] = t;
        }
#pragma unroll
        for (int i = 0; i < 2; ++i)
#pragma unroll
            for (int j = 0; j < 4; ++j)
                acc[i][j] = __builtin_amdgcn_mfma_f32_16x16x32_bf16(af[i], bf[j], acc[i][j], 0, 0, 0);
    }

    long long pbase = ((long long)ks*64 + zb)*8192;
#pragma unroll
    for (int i = 0; i < 2; ++i)
#pragma unroll
        for (int r = 0; r < 4; ++r) {
            int d2 = w*32 + i*16 + quad*4 + r;
#pragma unroll
            for (int j = 0; j < 4; ++j)
                part[pbase + d2*64 + j*16 + l16] = acc[i][j][r];
        }
}

// Bmat[z][d][j] = (sum_ks part[ks][z][sd][j]) / N, sd = j<32 ? d : (d+64)%128
__global__ void bmat_kernel(const float* __restrict__ part, float* __restrict__ bmat) {
    int idx = blockIdx.x * 256 + threadIdx.x;     // < 64*8192
    int z = idx >> 13, r = idx & 8191;
    int d = r >> 6, j = r & 63;
    int sd = (j < 32) ? d : ((d + 64) & 127);
    float s = 0.f;
#pragma unroll
    for (int ks = 0; ks < 7; ++ks)
        s += part[((long long)ks*64 + z)*8192 + (sd << 6) + j];
    bmat[idx] = s * (1.0f / (float)N_);
}

// z1/z2 per (b,h,n)
__global__ __launch_bounds__(256) void z_kernel(const float* __restrict__ qraw,
                                                const float* __restrict__ pw,
                                                const float* __restrict__ km,
                                                float* __restrict__ z1, float* __restrict__ z2)
{
    int zb = blockIdx.x;
    int b = zb >> 3, h = zb & 7;
    int n0 = blockIdx.y * 64;
    __shared__ float kmn[128];
    __shared__ float q[64][129];
    int tid = threadIdx.x;
    if (tid < 128) kmn[tid] = km[zb*128 + tid] * (1.0f / (float)N_);
    for (int i = tid; i < 64*64; i += 256) {
        int nl = i >> 6, d = i & 63;
        float qv = qraw[((long long)(b*N_ + n0 + nl))*512 + h*64 + d];
        float p = pw[h*64 + d];
        q[nl][d]      = safe_pow(qv, p);
        q[nl][d + 64] = safe_pow(-qv, p);
    }
    __syncthreads();
    int nl = tid >> 2, qtr = tid & 3;
    float p1 = 0.f, p2 = 0.f;
    int d0 = qtr * 32;
    for (int d = d0; d < d0 + 32; ++d) {
        p1 = fmaf(q[nl][d], kmn[d], p1);
        p2 = fmaf(q[nl][(d + 64) & 127], kmn[d], p2);
    }
    p1 += __shfl_xor(p1, 1); p1 += __shfl_xor(p1, 2);
    p2 += __shfl_xor(p2, 1); p2 += __shfl_xor(p2, 2);
    if (qtr == 0) {
        int n = n0 + nl;
        z1[(long long)zb*N_ + n] = 1.0f / (p1 + 1e-6f);
        z2[(long long)zb*N_ + n] = 1.0f / (p2 + 1e-6f);
    }
}

// attn = (qs @ bmat) * z -> bf16; qs powers computed on the fly from qraw
__global__ __launch_bounds__(256) void attn_gemm(const float* __restrict__ qraw,
                                                 const float* __restrict__ bmat,
                                                 const float* __restrict__ pw,
                                                 const float* __restrict__ z1,
                                                 const float* __restrict__ z2,
                                                 __hip_bfloat16* __restrict__ attnb)
{
    int zb = blockIdx.y;
    int b = zb >> 3, h = zb & 7;
    const float* Ab = qraw + (long long)b*N_*512 + h*64;
    const float* Bb = bmat + (long long)zb*8192;
    const float* pwh = pw + h*64;
    const int m0 = blockIdx.x * 64;
    const int tid = threadIdx.x;
    const int ty = tid >> 4, tx = tid & 15;
    const int arow = tid >> 2, acol = (tid & 3) * 4;
    const int brow = tid >> 4, bcol = (tid & 15) * 4;

    __shared__ float As[16][68];
    __shared__ float Bs[16][68];
    float acc[4][4] = {};

    for (int k0 = 0; k0 < 128; k0 += 16) {
        int kk = k0 + acol;
        int kb = kk & 63;
        float4 raw = *(const float4*)(Ab + (long long)(m0 + arow)*512 + kb);
        float sgn = (kk >= 64) ? -1.f : 1.f;
        float4 av;
        av.x = safe_pow(sgn*raw.x, pwh[kb+0]);
        av.y = safe_pow(sgn*raw.y, pwh[kb+1]);
        av.z = safe_pow(sgn*raw.z, pwh[kb+2]);
        av.w = safe_pow(sgn*raw.w, pwh[kb+3]);
        float4 bv = *(const float4*)(Bb + (long long)(k0 + brow)*64 + bcol);
        __syncthreads();
        As[acol+0][arow] = av.x;
        As[acol+1][arow] = av.y;
        As[acol+2][arow] = av.z;
        As[acol+3][arow] = av.w;
        *(float4*)&Bs[brow][bcol] = bv;
        __syncthreads();
#pragma unroll
        for (int kx = 0; kx < 16; ++kx) {
            float4 a4 = *(const float4*)&As[kx][ty*4];
            float4 b4 = *(const float4*)&Bs[kx][tx*4];
            float ar[4] = {a4.x, a4.y, a4.z, a4.w};
            float br[4] = {b4.x, b4.y, b4.z, b4.w};
#pragma unroll
            for (int i = 0; i < 4; ++i)
#pragma unroll
                for (int j = 0; j < 4; ++j)
                    acc[i][j] = fmaf(ar[i], br[j], acc[i][j]);
        }
    }
#pragma unroll
    for (int i = 0; i < 4; ++i) {
        int row = m0 + ty*4 + i;
#pragma unroll
        for (int j = 0; j < 4; ++j) {
            int col = tx*4 + j;
            float zz = ((col < 32) ? z1 : z2)[(long long)zb*N_ + row];
            attnb[((long long)(b*N_ + row))*512 + h*64 + col] = __float2bfloat16(acc[i][j] * zz);
        }
    }
}

// x2 = (attn + conv(v)+b)*g -> out (f32) and gx2 (bf16, in-place over g)
__global__ __launch_bounds__(256) void conv_combine(
    const __hip_bfloat16* __restrict__ vb, const float* __restrict__ dwc_w,
    const float* __restrict__ dwc_b, const __hip_bfloat16* __restrict__ attnb,
    __hip_bfloat16* __restrict__ gx2, float* __restrict__ out)
{
    __shared__ __hip_bfloat16 patch[8][32][64];
    __shared__ float wsh[1600];
    __shared__ float bsh[64];
    const int tid = threadIdx.x;
    const int zb = blockIdx.z;           // b*8+h
    const int b = zb >> 3, h = zb & 7;
    const int y0 = blockIdx.y * 4;       // 14 y-strips
    const int x0 = blockIdx.x * 28;      // 2 x-strips

    for (int i = tid; i < 1600; i += 256) wsh[i] = dwc_w[i];
    if (tid < 64) bsh[tid] = dwc_b[tid];

    for (int ci = tid; ci < 4096; ci += 256) {
        int c4 = ci & 15;
        int xs = (ci >> 4) & 31;
        int yy = ci >> 9;
        int gy = y0 - 2 + yy, gx = x0 - 2 + xs;
        uint2 val; val.x = 0u; val.y = 0u;
        if ((unsigned)gy < 56u && (unsigned)gx < 56u) {
            long long n = gy*56 + gx;
            val = *(const uint2*)(vb + ((long long)b*N_ + n)*512 + h*64 + c4*4);
        }
        *(uint2*)&patch[yy][xs][c4*4] = val;
    }
    __syncthreads();

    const int c = tid & 63;
    const int xg = tid >> 6;
    float wr[25];
#pragma unroll
    for (int t = 0; t < 25; ++t) wr[t] = wsh[c*25 + t];
    const float bias = bsh[c];
    const int C = h*64 + c;

    for (int yl = 0; yl < 4; ++yl) {
        for (int xi7 = 0; xi7 < 7; ++xi7) {
            int xi = xg*7 + xi7;
            float sum = bias;
#pragma unroll
            for (int ky = 0; ky < 5; ++ky)
#pragma unroll
                for (int kx = 0; kx < 5; ++kx)
                    sum = fmaf(wr[ky*5+kx],
                               __bfloat162float(patch[yl+ky][xi+kx][c]), sum);
            int n = (y0 + yl)*56 + x0 + xi;
            long long row = (long long)b*N_ + n;
            float attn = __bfloat162float(attnb[row*512 + C]);
            float g = __bfloat162float(gx2[row*512 + C]);
            float x2 = (attn + sum) * g;
            out[row*512 + C] = x2;
            gx2[row*512 + C] = __float2bfloat16(x2);
        }
    }
}

__global__ __launch_bounds__(256) void ln_kernel(float* __restrict__ y,
                                                 const float* __restrict__ g,
                                                 const float* __restrict__ bta)
{
    int wid = threadIdx.x >> 6, lane = threadIdx.x & 63;
    long long row = (long long)blockIdx.x*4 + wid;
    float v[8];
    float s = 0.f, s2 = 0.f;
#pragma unroll
    for (int i = 0; i < 8; ++i) {
        v[i] = y[row*512 + i*64 + lane];
        s += v[i];
        s2 = fmaf(v[i], v[i], s2);
    }
#pragma unroll
    for (int o = 32; o > 0; o >>= 1) { s += __shfl_xor(s, o); s2 += __shfl_xor(s2, o); }
    float mu = s * (1.f/512.f);
    float var = s2 * (1.f/512.f) - mu*mu;
    float rstd = rsqrtf(var + 1e-5f);
#pragma unroll
    for (int i = 0; i < 8; ++i) {
        int c = i*64 + lane;
        y[row*512 + c] = (v[i] - mu) * rstd * g[c] + bta[c];
    }
}

extern "C" void kernel_launch(void* const* d_in, const int* in_sizes, int n_in,
                              void* d_out, int out_size, void* d_ws, size_t ws_size,
                              hipStream_t stream)
{
    (void)in_sizes; (void)n_in; (void)out_size;
    if (ws_size < (size_t)WS_BYTES) return;  // fail loud (zero output), not crash

    const float* x       = (const float*)d_in[0];
    const float* Wqg     = (const float*)d_in[1];
    const float* Wkv     = (const float*)d_in[2];
    const float* pos     = (const float*)d_in[3];
    const float* scale_p = (const float*)d_in[4];
    const float* power_p = (const float*)d_in[5];
    const float* dwc_w   = (const float*)d_in[6];
    const float* dwc_b   = (const float*)d_in[7];
    const float* ln_g    = (const float*)d_in[8];
    const float* ln_b    = (const float*)d_in[9];
    const float* W1      = (const float*)d_in[10];
    const float* b1      = (const float*)d_in[11];
    const float* W2      = (const float*)d_in[12];
    const float* b2      = (const float*)d_in[13];
    float* out = (float*)d_out;
    char* ws   = (char*)d_ws;

    float* abuf  = (float*)(ws + OFF_A);           // kraw, then qraw
    __hip_bfloat16* kcT  = (__hip_bfloat16*)(ws + OFF_KCT);
    __hip_bfloat16* xb   = (__hip_bfloat16*)(ws + OFF_XB);
    __hip_bfloat16* vb   = (__hip_bfloat16*)(ws + OFF_VB);
    __hip_bfloat16* attnb= (__hip_bfloat16*)(ws + OFF_ATTN);
    float* part  = (float*)(ws + OFF_ATTN);        // aliases attnb (part dies first)
    __hip_bfloat16* gx2  = (__hip_bfloat16*)(ws + OFF_GX2);
    __hip_bfloat16* Wqgt = (__hip_bfloat16*)(ws + OFF_WQGT);
    __hip_bfloat16* Wkvt = (__hip_bfloat16*)(ws + OFF_WKVT);
    __hip_bfloat16* W1t  = (__hip_bfloat16*)(ws + OFF_W1T);
    __hip_bfloat16* W2t  = (__hip_bfloat16*)(ws + OFF_W2T);
    __hip_bfloat16* h1b  = (__hip_bfloat16*)(ws + OFF_H1B);
    float* km    = (float*)(ws + OFF_KM);
    float* bmat  = (float*)(ws + OFF_BMAT);
    float* z1    = (float*)(ws + OFF_Z1);
    float* z2    = (float*)(ws + OFF_Z2);
    float* sc    = (float*)(ws + OFF_SC);
    float* pw    = (float*)(ws + OFF_PW);

    prep_params<<<2, 256, 0, stream>>>(scale_p, power_p, sc, pw);
    zero_kernel<<<32, 256, 0, stream>>>(km, 64*128);
    cvt_bf16_kernel<<<(int)(((long long)M_*512/4 + 255)/256), 256, 0, stream>>>(x, xb, (long long)M_*512);
    transpose_cvt<<<dim3(32, 16), 256, 0, stream>>>(Wqg, Wqgt, 512, 1024);
    transpose_cvt<<<dim3(32, 16), 256, 0, stream>>>(Wkv, Wkvt, 512, 1024);
    transpose_cvt<<<dim3(128, 16), 256, 0, stream>>>(W1, W1t, 512, 4096);
    transpose_cvt<<<dim3(16, 128), 256, 0, stream>>>(W2, W2t, 4096, 512);

    // kv = x@Wkv -> kraw f32 (A slot) + v bf16
    gemm_mfma<1><<<dim3(8, 196), 256, 0, stream>>>(xb, 512, Wkvt, 512, 512, 0,
                                                   abuf, vb, sc, pos);
    // kraw -> kcT (bf16, transposed) + km ; then MFMA kvagg -> partials -> bmat
    kc_kernel<<<dim3(64, 49), 256, 0, stream>>>(abuf, pw, kcT, km);
    kvagg_mfma<<<dim3(7, 64), 256, 0, stream>>>(kcT, vb, part);
    bmat_kernel<<<2048, 256, 0, stream>>>(part, bmat);

    // qg = x@Wqg -> qraw f32 (A slot, kraw now dead) + g bf16
    gemm_mfma<0><<<dim3(8, 196), 256, 0, stream>>>(xb, 512, Wqgt, 512, 512, 0,
                                                   abuf, gx2, sc, nullptr);

    z_kernel<<<dim3(64, 49), 256, 0, stream>>>(abuf, pw, km, z1, z2);
    attn_gemm<<<dim3(49, 64), 256, 0, stream>>>(abuf, bmat, pw, z1, z2, attnb);

    conv_combine<<<dim3(2, 14, 64), 256, 0, stream>>>(vb, dwc_w, dwc_b, attnb, gx2, out);

    for (int c = 0; c < 2; ++c) {
        const __hip_bfloat16* x2c = gx2 + (long long)c*FFCHUNK*512;
        float* outc = out + (long long)c*FFCHUNK*512;
        gemm_mfma<2><<<dim3(32, FFCHUNK/128), 256, 0, stream>>>(
            x2c, 512, W1t, 512, 512, 4096, nullptr, h1b, b1, nullptr);
        gemm_mfma<3><<<dim3(4, FFCHUNK/128), 256, 0, stream>>>(
            h1b, 4096, W2t, 4096, 4096, 0, outc, nullptr, b2, nullptr);
    }

    ln_kernel<<<6272, 256, 0, stream>>>(out, ln_g, ln_b);
}